// Round 5
// baseline (609.776 us; speedup 1.0000x reference)
//
#include <hip/hip_runtime.h>
#include <math.h>

typedef __attribute__((ext_vector_type(4))) float f32x4;
typedef __attribute__((ext_vector_type(8))) short bf16x8;

__device__ __forceinline__ unsigned short f2bf(float f) {
  unsigned int u = __builtin_bit_cast(unsigned int, f);
  u += 0x7FFFu + ((u >> 16) & 1u);
  return (unsigned short)(u >> 16);
}

__device__ __forceinline__ f32x4 mfma16(bf16x8 a, bf16x8 b, f32x4 c) {
  return __builtin_amdgcn_mfma_f32_16x16x32_bf16(a, b, c, 0, 0, 0);
}

// ---------------- prep: fold BN into W (bf16) + bias (f32) ----------------
__global__ void prep_kernel(const float* __restrict__ W, const float* __restrict__ g,
                            const float* __restrict__ bb, const float* __restrict__ mm,
                            const float* __restrict__ vv,
                            unsigned short* __restrict__ Wout, float* __restrict__ bout,
                            float alpha) {
  int idx = blockIdx.x * 256 + threadIdx.x;
  if (idx < 192 * 192) {
    int o = idx / 192;
    float s = g[o] * rsqrtf(vv[o] + 1e-5f);
    Wout[idx] = f2bf(W[idx] * s * alpha);
  }
  if (idx < 192) {
    float s = g[idx] * rsqrtf(vv[idx] + 1e-5f);
    bout[idx] = (bb[idx] - mm[idx] * s) * alpha;
  }
}

// ---------------- projection: Y = relu(W' X + bias) ----------------
// X: [B][192][4096] f32.  LAYOUT 0: Y[b][o][hw] bf16; LAYOUT 1: Y[b][hw][o] bf16.
template <int LAYOUT>
__launch_bounds__(256)
__global__ void proj_kernel(const float* __restrict__ X,
                            const unsigned short* __restrict__ Wp,
                            const float* __restrict__ bias,
                            unsigned short* __restrict__ Yv) {
  const int o0 = blockIdx.x * 64;
  const int hw0 = blockIdx.y * 64;
  const int b = blockIdx.z;
  const int w = threadIdx.x >> 6, l = threadIdx.x & 63;
  const int l16 = l & 15, lg = l >> 4;
  const float* Xb = X + (size_t)b * 192 * 4096;

  f32x4 acc[4] = {f32x4{0,0,0,0}, f32x4{0,0,0,0}, f32x4{0,0,0,0}, f32x4{0,0,0,0}};

  for (int ks = 0; ks < 6; ++ks) {
    const int c0 = ks * 32 + lg * 8;
    bf16x8 a = *(const bf16x8*)(Wp + (size_t)(o0 + 16 * w + l16) * 192 + c0);
#pragma unroll
    for (int n = 0; n < 4; ++n) {
      const int hw = hw0 + 16 * n + l16;
      bf16x8 bfr;
#pragma unroll
      for (int j = 0; j < 8; ++j)
        bfr[j] = (short)f2bf(Xb[(size_t)(c0 + j) * 4096 + hw]);
      acc[n] = mfma16(a, bfr, acc[n]);
    }
  }

#pragma unroll
  for (int n = 0; n < 4; ++n) {
    const int hw = hw0 + 16 * n + l16;
    float vv4[4];
#pragma unroll
    for (int r = 0; r < 4; ++r) {
      const int o = o0 + 16 * w + lg * 4 + r;
      vv4[r] = fmaxf(acc[n][r] + bias[o], 0.0f);
    }
    if (LAYOUT == 1) {
      unsigned int lo = (unsigned)f2bf(vv4[0]) | ((unsigned)f2bf(vv4[1]) << 16);
      unsigned int hi = (unsigned)f2bf(vv4[2]) | ((unsigned)f2bf(vv4[3]) << 16);
      uint2 pk; pk.x = lo; pk.y = hi;
      *(uint2*)(Yv + ((size_t)b * 4096 + hw) * 192 + o0 + 16 * w + lg * 4) = pk;
    } else {
#pragma unroll
      for (int r = 0; r < 4; ++r) {
        const int o = o0 + 16 * w + lg * 4 + r;
        Yv[((size_t)b * 192 + o) * 4096 + hw] = f2bf(vv4[r]);
      }
    }
  }
}

// ---------------- final projection with NS-way partial-sum input (f32 out) ----------------
// X partials: NS slabs of [B][192][4096] f32, stride 4*192*4096 elements.
template <int NS>
__launch_bounds__(256)
__global__ void proj_sum_kernel(const float* __restrict__ X,
                                const unsigned short* __restrict__ Wp,
                                const float* __restrict__ bias,
                                float* __restrict__ Yv) {
  const int o0 = blockIdx.x * 64;
  const int hw0 = blockIdx.y * 64;
  const int b = blockIdx.z;
  const int w = threadIdx.x >> 6, l = threadIdx.x & 63;
  const int l16 = l & 15, lg = l >> 4;
  const float* Xb = X + (size_t)b * 192 * 4096;
  const size_t sstride = (size_t)4 * 192 * 4096;

  f32x4 acc[4] = {f32x4{0,0,0,0}, f32x4{0,0,0,0}, f32x4{0,0,0,0}, f32x4{0,0,0,0}};

  for (int ks = 0; ks < 6; ++ks) {
    const int c0 = ks * 32 + lg * 8;
    bf16x8 a = *(const bf16x8*)(Wp + (size_t)(o0 + 16 * w + l16) * 192 + c0);
#pragma unroll
    for (int n = 0; n < 4; ++n) {
      const int hw = hw0 + 16 * n + l16;
      bf16x8 bfr;
#pragma unroll
      for (int j = 0; j < 8; ++j) {
        float s = Xb[(size_t)(c0 + j) * 4096 + hw];
#pragma unroll
        for (int ss = 1; ss < NS; ++ss)
          s += Xb[(size_t)(c0 + j) * 4096 + hw + ss * sstride];
        bfr[j] = (short)f2bf(s);
      }
      acc[n] = mfma16(a, bfr, acc[n]);
    }
  }

#pragma unroll
  for (int n = 0; n < 4; ++n) {
    const int hw = hw0 + 16 * n + l16;
#pragma unroll
    for (int r = 0; r < 4; ++r) {
      const int o = o0 + 16 * w + lg * 4 + r;
      Yv[((size_t)b * 192 + o) * 4096 + hw] = fmaxf(acc[n][r] + bias[o], 0.0f);
    }
  }
}

// ---------------- pass 1: colsum[b][k] = sum_q exp2(S[q][k]) ----------------
__launch_bounds__(256)
__global__ void pass1_kernel(const unsigned short* __restrict__ qp,
                             const unsigned short* __restrict__ kpT,
                             float* __restrict__ colsum) {
  const int q0 = blockIdx.x * 128, k0 = blockIdx.y * 128, b = blockIdx.z;
  const int w = threadIdx.x >> 6, l = threadIdx.x & 63;
  const int l16 = l & 15, lg = l >> 4;
  const unsigned short* qb = qp + (size_t)b * 4096 * 192;
  const unsigned short* kb = kpT + (size_t)b * 4096 * 192;

  __shared__ __align__(16) unsigned short kpl[128][200];
  __shared__ float cs[4][128];

  {
    const int t = threadIdx.x;
#pragma unroll
    for (int i = 0; i < 12; ++i) {
      int idx = t + i * 256;
      int row = idx / 24, cu = idx % 24;
      uint4 vdat = *(const uint4*)(kb + (size_t)(k0 + row) * 192 + cu * 8);
      *(uint4*)&kpl[row][cu * 8] = vdat;
    }
  }
  __syncthreads();

  f32x4 acc[2][8];
#pragma unroll
  for (int m = 0; m < 2; ++m)
#pragma unroll
    for (int n = 0; n < 8; ++n) acc[m][n] = f32x4{0, 0, 0, 0};

  for (int ks = 0; ks < 6; ++ks) {
    const int c0 = ks * 32 + lg * 8;
    bf16x8 a0 = *(const bf16x8*)(qb + (size_t)(q0 + 32 * w + l16) * 192 + c0);
    bf16x8 a1 = *(const bf16x8*)(qb + (size_t)(q0 + 32 * w + 16 + l16) * 192 + c0);
#pragma unroll
    for (int n = 0; n < 8; ++n) {
      bf16x8 bfr = *(const bf16x8*)&kpl[16 * n + l16][c0];
      acc[0][n] = mfma16(a0, bfr, acc[0][n]);
      acc[1][n] = mfma16(a1, bfr, acc[1][n]);
    }
  }

  float part[8];
#pragma unroll
  for (int n = 0; n < 8; ++n) {
    float s = 0.f;
#pragma unroll
    for (int r = 0; r < 4; ++r)
      s += __builtin_amdgcn_exp2f(acc[0][n][r]) + __builtin_amdgcn_exp2f(acc[1][n][r]);
    s += __shfl_xor(s, 16);
    s += __shfl_xor(s, 32);
    part[n] = s;
  }
  if (l < 16) {
#pragma unroll
    for (int n = 0; n < 8; ++n) cs[w][16 * n + l] = part[n];
  }
  __syncthreads();
  const int t = threadIdx.x;
  if (t < 128) {
    float s = cs[0][t] + cs[1][t] + cs[2][t] + cs[3][t];
    atomicAdd(&colsum[(size_t)b * 4096 + k0 + t], s);
  }
}

__global__ void invert_kernel(float* __restrict__ p, int n) {
  int i = blockIdx.x * 256 + threadIdx.x;
  if (i < n) p[i] = 1.0f / p[i];
}

// ---------------- pass 2: barrier-free, LDS-free fused corr + PV ----------------
// Each wave owns 16 q-cols, sweeps a k-slab of 4096/NS. K-rows are loaded with
// permutation perm(m,u)=(m>>2)*8+u*4+(m&3) so the S^T accumulator pair (u=0,1)
// gives lane (lg,l16) exactly k=lg*8..+7 -> PV B-fragment is a pure f2bf repack.
// corr: per-lane f32x4 nontemporal stores. ss^T partial -> ssP slab per split.
template <int NS>
__launch_bounds__(256)
__global__ void pass2_kernel(const unsigned short* __restrict__ qp,
                             const unsigned short* __restrict__ kpT,
                             const unsigned short* __restrict__ vpN,
                             const float* __restrict__ rcol,
                             float* __restrict__ corr,
                             float* __restrict__ ssP) {
  const int gid = blockIdx.x;
  const int g = gid % (4 * NS);
  const int qpart = gid / (4 * NS);
  const int b = g / NS;
  const int s = g % NS;
  const int w = threadIdx.x >> 6, l = threadIdx.x & 63;
  const int l16 = l & 15, lg = l >> 4;
  const int q0 = qpart * 64 + w * 16;
  const int kbase = s * (4096 / NS);
  const int nchunk = (4096 / NS) / 64;

  const unsigned short* qb = qp + (size_t)b * 4096 * 192;
  const unsigned short* kb = kpT + (size_t)b * 4096 * 192;
  const unsigned short* vb = vpN + (size_t)b * 192 * 4096;
  const float* rc = rcol + (size_t)b * 4096;
  float* corb = corr + (size_t)b * 4096 * 4096;
  float* ssb = ssP + (size_t)(s * 4 + b) * 192 * 4096;

  const int permRow = ((l16 >> 2) * 8) + (l16 & 3);  // + u*4 gives physical k row
  const unsigned short* qrow = qb + (size_t)(q0 + l16) * 192 + lg * 8;
  float* corRow = corb + (size_t)(q0 + l16) * 4096;

  f32x4 ssa[12];
#pragma unroll
  for (int ct = 0; ct < 12; ++ct) ssa[ct] = f32x4{0, 0, 0, 0};

  for (int c = 0; c < nchunk; ++c) {
    const int k0 = kbase + c * 64;

    // ---- phase A: S^T sub-tiles (perm'd K rows) ----
    f32x4 sa[2][2];
#pragma unroll
    for (int p = 0; p < 2; ++p)
#pragma unroll
      for (int u = 0; u < 2; ++u) sa[p][u] = f32x4{0, 0, 0, 0};

    for (int ks = 0; ks < 6; ++ks) {
      bf16x8 qf = *(const bf16x8*)(qrow + ks * 32);
#pragma unroll
      for (int p = 0; p < 2; ++p)
#pragma unroll
        for (int u = 0; u < 2; ++u) {
          bf16x8 kf = *(const bf16x8*)(kb + (size_t)(k0 + p * 32 + u * 4 + permRow) * 192 + ks * 32 + lg * 8);
          sa[p][u] = mfma16(kf, qf, sa[p][u]);
        }
    }

    // ---- softmax-normalize, write corr, pack P fragments ----
    bf16x8 pfrag[2];
#pragma unroll
    for (int p = 0; p < 2; ++p) {
#pragma unroll
      for (int u = 0; u < 2; ++u) {
        const int kk = k0 + p * 32 + lg * 8 + u * 4;
        f32x4 rcv = *(const f32x4*)(rc + kk);
        f32x4 vals;
#pragma unroll
        for (int r = 0; r < 4; ++r)
          vals[r] = __builtin_amdgcn_exp2f(sa[p][u][r]) * rcv[r];
        __builtin_nontemporal_store(vals, (f32x4*)(corRow + kk));
#pragma unroll
        for (int r = 0; r < 4; ++r) pfrag[p][u * 4 + r] = (short)f2bf(vals[r]);
      }
    }

    // ---- phase B: ss^T += V^T @ P^T ----
#pragma unroll
    for (int ct = 0; ct < 12; ++ct) {
#pragma unroll
      for (int p = 0; p < 2; ++p) {
        bf16x8 vf = *(const bf16x8*)(vb + (size_t)(ct * 16 + l16) * 4096 + k0 + p * 32 + lg * 8);
        ssa[ct] = mfma16(vf, pfrag[p], ssa[ct]);
      }
    }
  }

  // ---- store ss^T partial: ssb[c][q] ----
#pragma unroll
  for (int ct = 0; ct < 12; ++ct)
#pragma unroll
    for (int r = 0; r < 4; ++r)
      ssb[(size_t)(ct * 16 + lg * 4 + r) * 4096 + q0 + l16] = ssa[ct][r];
}

// ---------------- launcher ----------------
extern "C" void kernel_launch(void* const* d_in, const int* in_sizes, int n_in,
                              void* d_out, int out_size, void* d_ws, size_t ws_size,
                              hipStream_t stream) {
  (void)in_sizes; (void)n_in; (void)out_size;
  const float* lr = (const float*)d_in[0];
  const float* refine = (const float*)d_in[1];

  char* ws = (char*)d_ws;
  unsigned short* w4 = (unsigned short*)(ws + 0);                       // 4*192*192 bf16
  float* bias4 = (float*)(ws + 294912);                                // 4*192 f32
  unsigned short* qp = (unsigned short*)(ws + 297984);                 // [4][4096][192] bf16
  unsigned short* kp = (unsigned short*)(ws + 297984 + 6291456);       // [4][4096][192] bf16
  unsigned short* vp = (unsigned short*)(ws + 297984 + 2 * 6291456);   // [4][192][4096] bf16
  float* colsum = (float*)(ws + 297984 + 3 * 6291456);                 // [4][4096] f32
  float* ssP = (float*)(ws + 297984 + 3 * 6291456 + 65536);            // [NS][4][192][4096] f32

  const size_t base = 297984 + (size_t)3 * 6291456 + 65536;
  const size_t slab = (size_t)4 * 192 * 4096 * 4;  // 12.58 MB per split
  int NS = 1;
  if (ws_size >= base + 4 * slab) NS = 4;
  else if (ws_size >= base + 2 * slab) NS = 2;

  float* out0 = (float*)d_out;
  float* corr = out0 + 3145728;  // [4][4096][4096] f32

  const float alpha = (float)(1.4426950408889634 / sqrt(192.0));  // log2(e)/sqrt(C)

  for (int p = 0; p < 4; ++p) {
    prep_kernel<<<dim3(144), dim3(256), 0, stream>>>(
        (const float*)d_in[2 + 5 * p], (const float*)d_in[3 + 5 * p],
        (const float*)d_in[4 + 5 * p], (const float*)d_in[5 + 5 * p],
        (const float*)d_in[6 + 5 * p],
        w4 + p * 36864, bias4 + p * 192, p == 0 ? alpha : 1.0f);
  }
  hipMemsetAsync(colsum, 0, 65536, stream);

  // q from refine (transposed, scaled via W); k from lr (transposed); v from lr (natural)
  proj_kernel<1><<<dim3(3, 64, 4), dim3(256), 0, stream>>>(refine, w4, bias4, qp);
  proj_kernel<1><<<dim3(3, 64, 4), dim3(256), 0, stream>>>(lr, w4 + 36864, bias4 + 192, kp);
  proj_kernel<0><<<dim3(3, 64, 4), dim3(256), 0, stream>>>(lr, w4 + 2 * 36864, bias4 + 2 * 192, vp);

  pass1_kernel<<<dim3(32, 32, 4), dim3(256), 0, stream>>>(qp, kp, colsum);
  invert_kernel<<<dim3(64), dim3(256), 0, stream>>>(colsum, 16384);

  if (NS == 4)
    pass2_kernel<4><<<dim3(64 * 16), dim3(256), 0, stream>>>(qp, kp, vp, colsum, corr, ssP);
  else if (NS == 2)
    pass2_kernel<2><<<dim3(64 * 8), dim3(256), 0, stream>>>(qp, kp, vp, colsum, corr, ssP);
  else
    pass2_kernel<1><<<dim3(64 * 4), dim3(256), 0, stream>>>(qp, kp, vp, colsum, corr, ssP);

  if (NS == 4)
    proj_sum_kernel<4><<<dim3(3, 64, 4), dim3(256), 0, stream>>>(ssP, w4 + 3 * 36864, bias4 + 3 * 192, out0);
  else if (NS == 2)
    proj_sum_kernel<2><<<dim3(3, 64, 4), dim3(256), 0, stream>>>(ssP, w4 + 3 * 36864, bias4 + 3 * 192, out0);
  else
    proj_sum_kernel<1><<<dim3(3, 64, 4), dim3(256), 0, stream>>>(ssP, w4 + 3 * 36864, bias4 + 3 * 192, out0);
}

// Round 6
// 293.809 us; speedup vs baseline: 2.0754x; 2.0754x over previous
//
#include <hip/hip_runtime.h>
#include <math.h>

typedef __attribute__((ext_vector_type(4))) float f32x4;
typedef __attribute__((ext_vector_type(8))) short bf16x8;

__device__ __forceinline__ unsigned short f2bf(float f) {
  unsigned int u = __builtin_bit_cast(unsigned int, f);
  u += 0x7FFFu + ((u >> 16) & 1u);
  return (unsigned short)(u >> 16);
}

__device__ __forceinline__ f32x4 mfma16(bf16x8 a, bf16x8 b, f32x4 c) {
  return __builtin_amdgcn_mfma_f32_16x16x32_bf16(a, b, c, 0, 0, 0);
}

// ---------------- prep: fold BN into W (bf16) + bias (f32) ----------------
__global__ void prep_kernel(const float* __restrict__ W, const float* __restrict__ g,
                            const float* __restrict__ bb, const float* __restrict__ mm,
                            const float* __restrict__ vv,
                            unsigned short* __restrict__ Wout, float* __restrict__ bout,
                            float alpha) {
  int idx = blockIdx.x * 256 + threadIdx.x;
  if (idx < 192 * 192) {
    int o = idx / 192;
    float s = g[o] * rsqrtf(vv[o] + 1e-5f);
    Wout[idx] = f2bf(W[idx] * s * alpha);
  }
  if (idx < 192) {
    float s = g[idx] * rsqrtf(vv[idx] + 1e-5f);
    bout[idx] = (bb[idx] - mm[idx] * s) * alpha;
  }
}

// ---------------- projection: Y = relu(W' X + bias) ----------------
// X: [B][192][4096] f32.  LAYOUT 0: Y[b][o][hw] bf16; LAYOUT 1: Y[b][hw][o] bf16.
template <int LAYOUT>
__launch_bounds__(256)
__global__ void proj_kernel(const float* __restrict__ X,
                            const unsigned short* __restrict__ Wp,
                            const float* __restrict__ bias,
                            unsigned short* __restrict__ Yv) {
  const int o0 = blockIdx.x * 64;
  const int hw0 = blockIdx.y * 64;
  const int b = blockIdx.z;
  const int w = threadIdx.x >> 6, l = threadIdx.x & 63;
  const int l16 = l & 15, lg = l >> 4;
  const float* Xb = X + (size_t)b * 192 * 4096;

  f32x4 acc[4] = {f32x4{0,0,0,0}, f32x4{0,0,0,0}, f32x4{0,0,0,0}, f32x4{0,0,0,0}};

  for (int ks = 0; ks < 6; ++ks) {
    const int c0 = ks * 32 + lg * 8;
    bf16x8 a = *(const bf16x8*)(Wp + (size_t)(o0 + 16 * w + l16) * 192 + c0);
#pragma unroll
    for (int n = 0; n < 4; ++n) {
      const int hw = hw0 + 16 * n + l16;
      bf16x8 bfr;
#pragma unroll
      for (int j = 0; j < 8; ++j)
        bfr[j] = (short)f2bf(Xb[(size_t)(c0 + j) * 4096 + hw]);
      acc[n] = mfma16(a, bfr, acc[n]);
    }
  }

#pragma unroll
  for (int n = 0; n < 4; ++n) {
    const int hw = hw0 + 16 * n + l16;
    float vv4[4];
#pragma unroll
    for (int r = 0; r < 4; ++r) {
      const int o = o0 + 16 * w + lg * 4 + r;
      vv4[r] = fmaxf(acc[n][r] + bias[o], 0.0f);
    }
    if (LAYOUT == 1) {
      unsigned int lo = (unsigned)f2bf(vv4[0]) | ((unsigned)f2bf(vv4[1]) << 16);
      unsigned int hi = (unsigned)f2bf(vv4[2]) | ((unsigned)f2bf(vv4[3]) << 16);
      uint2 pk; pk.x = lo; pk.y = hi;
      *(uint2*)(Yv + ((size_t)b * 4096 + hw) * 192 + o0 + 16 * w + lg * 4) = pk;
    } else {
#pragma unroll
      for (int r = 0; r < 4; ++r) {
        const int o = o0 + 16 * w + lg * 4 + r;
        Yv[((size_t)b * 192 + o) * 4096 + hw] = f2bf(vv4[r]);
      }
    }
  }
}

// ---------------- final projection with NS-way partial-sum input (f32 out) ----------------
template <int NS>
__launch_bounds__(256)
__global__ void proj_sum_kernel(const float* __restrict__ X,
                                const unsigned short* __restrict__ Wp,
                                const float* __restrict__ bias,
                                float* __restrict__ Yv) {
  const int o0 = blockIdx.x * 64;
  const int hw0 = blockIdx.y * 64;
  const int b = blockIdx.z;
  const int w = threadIdx.x >> 6, l = threadIdx.x & 63;
  const int l16 = l & 15, lg = l >> 4;
  const float* Xb = X + (size_t)b * 192 * 4096;
  const size_t sstride = (size_t)4 * 192 * 4096;

  f32x4 acc[4] = {f32x4{0,0,0,0}, f32x4{0,0,0,0}, f32x4{0,0,0,0}, f32x4{0,0,0,0}};

  for (int ks = 0; ks < 6; ++ks) {
    const int c0 = ks * 32 + lg * 8;
    bf16x8 a = *(const bf16x8*)(Wp + (size_t)(o0 + 16 * w + l16) * 192 + c0);
#pragma unroll
    for (int n = 0; n < 4; ++n) {
      const int hw = hw0 + 16 * n + l16;
      bf16x8 bfr;
#pragma unroll
      for (int j = 0; j < 8; ++j) {
        float s = Xb[(size_t)(c0 + j) * 4096 + hw];
#pragma unroll
        for (int ss = 1; ss < NS; ++ss)
          s += Xb[(size_t)(c0 + j) * 4096 + hw + ss * sstride];
        bfr[j] = (short)f2bf(s);
      }
      acc[n] = mfma16(a, bfr, acc[n]);
    }
  }

#pragma unroll
  for (int n = 0; n < 4; ++n) {
    const int hw = hw0 + 16 * n + l16;
#pragma unroll
    for (int r = 0; r < 4; ++r) {
      const int o = o0 + 16 * w + lg * 4 + r;
      Yv[((size_t)b * 192 + o) * 4096 + hw] = fmaxf(acc[n][r] + bias[o], 0.0f);
    }
  }
}

// ---------------- pass 1: colsum[b][k] = sum_q exp2(S[q][k]) ----------------
__launch_bounds__(256)
__global__ void pass1_kernel(const unsigned short* __restrict__ qp,
                             const unsigned short* __restrict__ kpT,
                             float* __restrict__ colsum) {
  const int q0 = blockIdx.x * 128, k0 = blockIdx.y * 128, b = blockIdx.z;
  const int w = threadIdx.x >> 6, l = threadIdx.x & 63;
  const int l16 = l & 15, lg = l >> 4;
  const unsigned short* qb = qp + (size_t)b * 4096 * 192;
  const unsigned short* kb = kpT + (size_t)b * 4096 * 192;

  __shared__ __align__(16) unsigned short kpl[128][200];
  __shared__ float cs[4][128];

  {
    const int t = threadIdx.x;
#pragma unroll
    for (int i = 0; i < 12; ++i) {
      int idx = t + i * 256;
      int row = idx / 24, cu = idx % 24;
      uint4 vdat = *(const uint4*)(kb + (size_t)(k0 + row) * 192 + cu * 8);
      *(uint4*)&kpl[row][cu * 8] = vdat;
    }
  }
  __syncthreads();

  f32x4 acc[2][8];
#pragma unroll
  for (int m = 0; m < 2; ++m)
#pragma unroll
    for (int n = 0; n < 8; ++n) acc[m][n] = f32x4{0, 0, 0, 0};

  for (int ks = 0; ks < 6; ++ks) {
    const int c0 = ks * 32 + lg * 8;
    bf16x8 a0 = *(const bf16x8*)(qb + (size_t)(q0 + 32 * w + l16) * 192 + c0);
    bf16x8 a1 = *(const bf16x8*)(qb + (size_t)(q0 + 32 * w + 16 + l16) * 192 + c0);
#pragma unroll
    for (int n = 0; n < 8; ++n) {
      bf16x8 bfr = *(const bf16x8*)&kpl[16 * n + l16][c0];
      acc[0][n] = mfma16(a0, bfr, acc[0][n]);
      acc[1][n] = mfma16(a1, bfr, acc[1][n]);
    }
  }

  float part[8];
#pragma unroll
  for (int n = 0; n < 8; ++n) {
    float s = 0.f;
#pragma unroll
    for (int r = 0; r < 4; ++r)
      s += __builtin_amdgcn_exp2f(acc[0][n][r]) + __builtin_amdgcn_exp2f(acc[1][n][r]);
    s += __shfl_xor(s, 16);
    s += __shfl_xor(s, 32);
    part[n] = s;
  }
  if (l < 16) {
#pragma unroll
    for (int n = 0; n < 8; ++n) cs[w][16 * n + l] = part[n];
  }
  __syncthreads();
  const int t = threadIdx.x;
  if (t < 128) {
    float s = cs[0][t] + cs[1][t] + cs[2][t] + cs[3][t];
    atomicAdd(&colsum[(size_t)b * 4096 + k0 + t], s);
  }
}

__global__ void invert_kernel(float* __restrict__ p, int n) {
  int i = blockIdx.x * 256 + threadIdx.x;
  if (i < n) p[i] = 1.0f / p[i];
}

// ---------------- pass 2: round-1 structure + NS-way k-split into private slabs ----------------
// grid (64 q-blocks, NS, 4 b), 512 threads. Per block: af preload, per-chunk
// {QK^T MFMA -> exp2*rcol -> LDS cor -> nt corr store + PV MFMA}. ss partials to ssP slab.
template <int NS>
__launch_bounds__(512)
__global__ void pass2_kernel(const unsigned short* __restrict__ qp,
                             const unsigned short* __restrict__ kpT,
                             const unsigned short* __restrict__ vpN,
                             const float* __restrict__ rcol,
                             float* __restrict__ corr,
                             float* __restrict__ ssP) {
  const int q0 = blockIdx.x * 64;
  const int s = blockIdx.y;
  const int b = blockIdx.z;
  const int kc0 = s * (32 / NS);
  const int w = threadIdx.x >> 6, l = threadIdx.x & 63;
  const int l16 = l & 15, lg = l >> 4;
  const int mw = w & 1, nw = w >> 1;  // 2x4 wave grid
  const unsigned short* qb = qp + (size_t)b * 4096 * 192;
  const unsigned short* kb = kpT + (size_t)b * 4096 * 192;
  const unsigned short* vb = vpN + (size_t)b * 192 * 4096;
  const float* rc = rcol + (size_t)b * 4096;
  float* corb = corr + (size_t)b * 4096 * 4096;
  float* ssb = ssP + (size_t)(s * 4 + b) * 192 * 4096;

  __shared__ __align__(16) float cor[64][132];  // padded stride (bank-safe)

  // preload A fragments (chunk-invariant)
  bf16x8 af[2][6];
#pragma unroll
  for (int tm = 0; tm < 2; ++tm)
#pragma unroll
    for (int ks = 0; ks < 6; ++ks)
      af[tm][ks] = *(const bf16x8*)(qb + (size_t)(q0 + 16 * (2 * mw + tm) + l16) * 192 + ks * 32 + lg * 8);

  f32x4 ssa[2][3];
#pragma unroll
  for (int tm = 0; tm < 2; ++tm)
#pragma unroll
    for (int j = 0; j < 3; ++j) ssa[tm][j] = f32x4{0, 0, 0, 0};

  for (int kc = kc0; kc < kc0 + 32 / NS; ++kc) {
    const int k0 = kc * 128;
    // ---- phase A: S tiles ----
    f32x4 sa[2][2];
#pragma unroll
    for (int tm = 0; tm < 2; ++tm)
#pragma unroll
      for (int tn = 0; tn < 2; ++tn) sa[tm][tn] = f32x4{0, 0, 0, 0};

    for (int ks = 0; ks < 6; ++ks) {
      const int c0 = ks * 32 + lg * 8;
#pragma unroll
      for (int tn = 0; tn < 2; ++tn) {
        const int kcol = k0 + 16 * (2 * nw + tn) + l16;
        bf16x8 bfr = *(const bf16x8*)(kb + (size_t)kcol * 192 + c0);
        sa[0][tn] = mfma16(af[0][ks], bfr, sa[0][tn]);
        sa[1][tn] = mfma16(af[1][ks], bfr, sa[1][tn]);
      }
    }
    float rcv[2];
#pragma unroll
    for (int tn = 0; tn < 2; ++tn) rcv[tn] = rc[k0 + 16 * (2 * nw + tn) + l16];
#pragma unroll
    for (int tm = 0; tm < 2; ++tm)
#pragma unroll
      for (int tn = 0; tn < 2; ++tn)
#pragma unroll
        for (int r = 0; r < 4; ++r)
          sa[tm][tn][r] = __builtin_amdgcn_exp2f(sa[tm][tn][r]) * rcv[tn];

    __syncthreads();  // previous chunk's LDS readers done
#pragma unroll
    for (int tm = 0; tm < 2; ++tm)
#pragma unroll
      for (int tn = 0; tn < 2; ++tn) {
        const int col = 16 * (2 * nw + tn) + l16;
#pragma unroll
        for (int r = 0; r < 4; ++r)
          cor[16 * (2 * mw + tm) + lg * 4 + r][col] = sa[tm][tn][r];
      }
    __syncthreads();  // LDS writes visible

    // ---- corr chunk -> global (row-contiguous 16B nontemporal stores) ----
    {
      const int t = threadIdx.x;
#pragma unroll
      for (int it = 0; it < 4; ++it) {
        int idx = t + it * 512;
        int row = idx >> 5, seg = idx & 31;
        f32x4 v4 = *(const f32x4*)&cor[row][seg * 4];
        __builtin_nontemporal_store(v4, (f32x4*)(corb + (size_t)(q0 + row) * 4096 + k0 + seg * 4));
      }
    }

    // ---- phase B: ss += corr_chunk @ v ----
#pragma unroll
    for (int ks2 = 0; ks2 < 4; ++ks2) {
      const int cc = ks2 * 32 + lg * 8;
      bf16x8 pa[2];
#pragma unroll
      for (int tm = 0; tm < 2; ++tm) {
        f32x4 p0 = *(const f32x4*)&cor[16 * (2 * mw + tm) + l16][cc];
        f32x4 p1 = *(const f32x4*)&cor[16 * (2 * mw + tm) + l16][cc + 4];
#pragma unroll
        for (int j = 0; j < 4; ++j) {
          pa[tm][j] = (short)f2bf(p0[j]);
          pa[tm][j + 4] = (short)f2bf(p1[j]);
        }
      }
#pragma unroll
      for (int j = 0; j < 3; ++j) {
        const int ccol = 16 * (nw + 4 * j) + l16;
        bf16x8 bfr = *(const bf16x8*)(vb + (size_t)ccol * 4096 + k0 + cc);
        ssa[0][j] = mfma16(pa[0], bfr, ssa[0][j]);
        ssa[1][j] = mfma16(pa[1], bfr, ssa[1][j]);
      }
    }
  }

  // ---- store ss partial (transposed) into this split's private slab ----
#pragma unroll
  for (int tm = 0; tm < 2; ++tm)
#pragma unroll
    for (int j = 0; j < 3; ++j) {
      const int ccol = 16 * (nw + 4 * j) + l16;
#pragma unroll
      for (int r = 0; r < 4; ++r) {
        const int qrow = q0 + 16 * (2 * mw + tm) + lg * 4 + r;
        ssb[(size_t)ccol * 4096 + qrow] = ssa[tm][j][r];
      }
    }
}

// ---------------- launcher ----------------
extern "C" void kernel_launch(void* const* d_in, const int* in_sizes, int n_in,
                              void* d_out, int out_size, void* d_ws, size_t ws_size,
                              hipStream_t stream) {
  (void)in_sizes; (void)n_in; (void)out_size;
  const float* lr = (const float*)d_in[0];
  const float* refine = (const float*)d_in[1];

  char* ws = (char*)d_ws;
  unsigned short* w4 = (unsigned short*)(ws + 0);                       // 4*192*192 bf16
  float* bias4 = (float*)(ws + 294912);                                // 4*192 f32
  unsigned short* qp = (unsigned short*)(ws + 297984);                 // [4][4096][192] bf16
  unsigned short* kp = (unsigned short*)(ws + 297984 + 6291456);       // [4][4096][192] bf16
  unsigned short* vp = (unsigned short*)(ws + 297984 + 2 * 6291456);   // [4][192][4096] bf16
  float* colsum = (float*)(ws + 297984 + 3 * 6291456);                 // [4][4096] f32
  float* ssP = (float*)(ws + 297984 + 3 * 6291456 + 65536);            // [NS][4][192][4096] f32

  const size_t base = 297984 + (size_t)3 * 6291456 + 65536;
  const size_t slab = (size_t)4 * 192 * 4096 * 4;  // 12.58 MB per split
  int NS = (ws_size >= base + 2 * slab) ? 2 : 1;

  float* out0 = (float*)d_out;
  float* corr = out0 + 3145728;  // [4][4096][4096] f32

  const float alpha = (float)(1.4426950408889634 / sqrt(192.0));  // log2(e)/sqrt(C)

  for (int p = 0; p < 4; ++p) {
    prep_kernel<<<dim3(144), dim3(256), 0, stream>>>(
        (const float*)d_in[2 + 5 * p], (const float*)d_in[3 + 5 * p],
        (const float*)d_in[4 + 5 * p], (const float*)d_in[5 + 5 * p],
        (const float*)d_in[6 + 5 * p],
        w4 + p * 36864, bias4 + p * 192, p == 0 ? alpha : 1.0f);
  }
  hipMemsetAsync(colsum, 0, 65536, stream);

  proj_kernel<1><<<dim3(3, 64, 4), dim3(256), 0, stream>>>(refine, w4, bias4, qp);
  proj_kernel<1><<<dim3(3, 64, 4), dim3(256), 0, stream>>>(lr, w4 + 36864, bias4 + 192, kp);
  proj_kernel<0><<<dim3(3, 64, 4), dim3(256), 0, stream>>>(lr, w4 + 2 * 36864, bias4 + 2 * 192, vp);

  pass1_kernel<<<dim3(32, 32, 4), dim3(256), 0, stream>>>(qp, kp, colsum);
  invert_kernel<<<dim3(64), dim3(256), 0, stream>>>(colsum, 16384);

  if (NS == 2) {
    pass2_kernel<2><<<dim3(64, 2, 4), dim3(512), 0, stream>>>(qp, kp, vp, colsum, corr, ssP);
    proj_sum_kernel<2><<<dim3(3, 64, 4), dim3(256), 0, stream>>>(ssP, w4 + 3 * 36864, bias4 + 3 * 192, out0);
  } else {
    pass2_kernel<1><<<dim3(64, 1, 4), dim3(512), 0, stream>>>(qp, kp, vp, colsum, corr, ssP);
    proj_sum_kernel<1><<<dim3(3, 64, 4), dim3(256), 0, stream>>>(ssP, w4 + 3 * 36864, bias4 + 3 * 192, out0);
  }
}